// Round 9
// baseline (395.022 us; speedup 1.0000x reference)
//
#include <hip/hip_runtime.h>
#include <hip/hip_bf16.h>

// B=2, N=2048, D=1024, H=16, DH=64. Output fp32; inputs runtime-detected
// fp32-vs-bf16, converted once. R9:
//  (a) attention via 16x16x16 MFMA transpose trick: S^T=K.Q^T C-layout
//      (row=quad*4+r) == k16 B-frag k-index (k=quad*4+j), so exp2(S^T) is
//      directly the B operand of O^T=V^T.P^T. No LDS, no barriers, 1-wave blocks.
//  (b) weights pre-transposed (W^T[n][k]) so GEMM Bs staging is vectorized
//      b128 (removes 16-way scatter).
//
// ws (bf16 elems): Q@0(4M), K@4M, Vt@8M, Xc/AO@12M (shared), WqT@16M, WkT@17M,
// WvT@18M, WoT@19M, boc@20M. ~40MB.

typedef __bf16 bf16x8 __attribute__((ext_vector_type(8)));
typedef float f32x4 __attribute__((ext_vector_type(4)));
typedef short s4 __attribute__((ext_vector_type(4)));      // k16 MFMA A/B frag (4 bf16)
typedef unsigned short ushort_t;

#define MFMA_16x16x32(a, b, c) __builtin_amdgcn_mfma_f32_16x16x32_bf16(a, b, c, 0, 0, 0)
#define MFMA16(a, b, c) __builtin_amdgcn_mfma_f32_16x16x16bf16_1k(a, b, c, 0, 0, 0)

__device__ __forceinline__ ushort_t f2bf(float f) {
    __hip_bfloat16 h = __float2bfloat16(f);
    return __builtin_bit_cast(ushort_t, h);
}
__device__ __forceinline__ float bf2f(ushort_t u) {
    unsigned x = ((unsigned)u) << 16;
    return __builtin_bit_cast(float, x);
}

// Wave-uniform dtype probe (weights ~N(0,0.02^2): bf16 words never have exp>=0x7F).
__device__ __forceinline__ unsigned detect_fp32(const void* wp) {
    const ushort_t* w = (const ushort_t*)wp;
    unsigned c = 0;
    #pragma unroll
    for (int i = 0; i < 128; ++i) c += (((w[i] >> 7) & 0xFF) >= 0x7F) ? 1u : 0u;
    return (c > 8) ? 1u : 0u;
}

__device__ __forceinline__ uint4 load8(const void* p, size_t idx, unsigned flag) {
    if (flag) {
        const float* f = (const float*)p + idx;
        float4 a = *(const float4*)f;
        float4 b = *(const float4*)(f + 4);
        ushort_t u[8] = { f2bf(a.x), f2bf(a.y), f2bf(a.z), f2bf(a.w),
                          f2bf(b.x), f2bf(b.y), f2bf(b.z), f2bf(b.w) };
        return *(uint4*)u;
    }
    return *(const uint4*)((const ushort_t*)p + idx);
}

// ---------------- convert X + bias to bf16 ----------------
__global__ __launch_bounds__(256) void convert_x(
    const void* __restrict__ X, const void* __restrict__ Wq, const void* __restrict__ bo,
    ushort_t* __restrict__ Xc, ushort_t* __restrict__ boc)
{
    const unsigned flag = detect_fp32(Wq);
    const int blk = blockIdx.x;
    if (blk < 2048) {
        size_t idx = (size_t)blk * 2048 + (size_t)threadIdx.x * 8;
        *(uint4*)(Xc + idx) = load8(X, idx, flag);
    } else {
        size_t idx = (size_t)threadIdx.x * 8;
        if (idx < 1024) *(uint4*)(boc + idx) = load8(bo, idx, flag);
    }
}

// ---------------- transpose weights -> WT[n][k], converting to bf16 ----------------
// grid (16, 16, 4), block 256; 64x64 tiles via LDS.
__global__ __launch_bounds__(256) void transpose_w(
    const void* __restrict__ Wq, const void* __restrict__ Wk,
    const void* __restrict__ Wv, const void* __restrict__ Wo,
    ushort_t* __restrict__ WqT, ushort_t* __restrict__ WkT,
    ushort_t* __restrict__ WvT, ushort_t* __restrict__ WoT)
{
    __shared__ ushort_t T[64][72];   // stride 72 shorts = 144B (16B-mult)
    const unsigned flag = detect_fp32(Wq);
    const int z = blockIdx.z;
    const void* W = (z == 0) ? Wq : ((z == 1) ? Wk : ((z == 2) ? Wv : Wo));
    ushort_t* WT = (z == 0) ? WqT : ((z == 1) ? WkT : ((z == 2) ? WvT : WoT));

    const int k0 = blockIdx.y * 64, n0 = blockIdx.x * 64;
    const int r = threadIdx.x >> 2, c = (threadIdx.x & 3) * 16;

    *(uint4*)&T[r][c]     = load8(W, (size_t)(k0 + r) * 1024 + n0 + c,     flag);
    *(uint4*)&T[r][c + 8] = load8(W, (size_t)(k0 + r) * 1024 + n0 + c + 8, flag);
    __syncthreads();
    ushort_t tmp[16];
    #pragma unroll
    for (int j = 0; j < 16; ++j) tmp[j] = T[c + j][r];
    *(uint4*)(WT + (size_t)(n0 + r) * 1024 + k0 + c)     = *(uint4*)&tmp[0];
    *(uint4*)(WT + (size_t)(n0 + r) * 1024 + k0 + c + 8) = *(uint4*)&tmp[8];
}

// ---------------- QKV projection GEMM, 128x128 tile, bf16, W^T input ----------------
// grid (8, 32, 3), block 256 (4 waves), BK=32. z=0->Q, z=1->K; z=2->Vt[B][H][DH][N].
__global__ __launch_bounds__(256) void qkv_gemm(
    const ushort_t* __restrict__ X, const ushort_t* __restrict__ WqT,
    const ushort_t* __restrict__ WkT, const ushort_t* __restrict__ WvT,
    ushort_t* __restrict__ Q, ushort_t* __restrict__ K, ushort_t* __restrict__ Vt)
{
    __shared__ ushort_t As[128 * 40];
    __shared__ ushort_t Bs[128 * 40];   // Bs[n][k]

    const int z = blockIdx.z;
    const ushort_t* WT = (z == 0) ? WqT : ((z == 1) ? WkT : WvT);

    const int tid  = threadIdx.x;
    const int m0   = blockIdx.y * 128, n0 = blockIdx.x * 128;
    const int lane = tid & 63, wv = tid >> 6;
    const int quad = lane >> 4, l15 = lane & 15;
    const int wm = (wv & 1) * 64, wn = (wv >> 1) * 64;

    const int ar = tid >> 1, ac = (tid & 1) * 16;   // 128 rows x 32 k

    f32x4 acc[4][4] = {};

    uint4 ra0 = *(const uint4*)(X  + (size_t)(m0 + ar) * 1024 + ac);
    uint4 ra1 = *(const uint4*)(X  + (size_t)(m0 + ar) * 1024 + ac + 8);
    uint4 rb0 = *(const uint4*)(WT + (size_t)(n0 + ar) * 1024 + ac);
    uint4 rb1 = *(const uint4*)(WT + (size_t)(n0 + ar) * 1024 + ac + 8);

    for (int kt = 0; kt < 32; ++kt) {
        __syncthreads();
        *(uint4*)(As + ar * 40 + ac)     = ra0;
        *(uint4*)(As + ar * 40 + ac + 8) = ra1;
        *(uint4*)(Bs + ar * 40 + ac)     = rb0;
        *(uint4*)(Bs + ar * 40 + ac + 8) = rb1;
        __syncthreads();
        if (kt < 31) {
            int k0 = (kt + 1) * 32;
            ra0 = *(const uint4*)(X  + (size_t)(m0 + ar) * 1024 + k0 + ac);
            ra1 = *(const uint4*)(X  + (size_t)(m0 + ar) * 1024 + k0 + ac + 8);
            rb0 = *(const uint4*)(WT + (size_t)(n0 + ar) * 1024 + k0 + ac);
            rb1 = *(const uint4*)(WT + (size_t)(n0 + ar) * 1024 + k0 + ac + 8);
        }
        bf16x8 af[4], bfr[4];
        #pragma unroll
        for (int t = 0; t < 4; ++t) {
            af[t]  = *(const bf16x8*)(As + (wm + t * 16 + l15) * 40 + quad * 8);
            bfr[t] = *(const bf16x8*)(Bs + (wn + t * 16 + l15) * 40 + quad * 8);
        }
        #pragma unroll
        for (int mt = 0; mt < 4; ++mt)
            #pragma unroll
            for (int nt = 0; nt < 4; ++nt)
                acc[mt][nt] = MFMA_16x16x32(af[mt], bfr[nt], acc[mt][nt]);
    }

    #pragma unroll
    for (int mt = 0; mt < 4; ++mt) {
        #pragma unroll
        for (int nt = 0; nt < 4; ++nt) {
            if (z == 2) {
                int c  = n0 + wn + nt * 16 + l15;
                int h  = c >> 6, dh = c & 63;
                int mA = m0 + wm + mt * 16 + quad * 4;
                int b  = mA >> 11, nseq = mA & 2047;
                ushort_t pk[4];
                #pragma unroll
                for (int r = 0; r < 4; ++r) pk[r] = f2bf(acc[mt][nt][r]);
                *(ushort2*)(Vt + ((size_t)((b * 16 + h) * 64 + dh)) * 2048 + nseq)     = *(ushort2*)&pk[0];
                *(ushort2*)(Vt + ((size_t)((b * 16 + h) * 64 + dh)) * 2048 + nseq + 2) = *(ushort2*)&pk[2];
            } else {
                ushort_t* dst = (z == 0) ? Q : K;
                #pragma unroll
                for (int r = 0; r < 4; ++r) {
                    int m = m0 + wm + mt * 16 + quad * 4 + r;
                    int c = n0 + wn + nt * 16 + l15;
                    int b = m >> 11, nseq = m & 2047;
                    int h = c >> 6, dh = c & 63;
                    dst[((size_t)((b * 16 + h) * 2048 + nseq)) * 64 + dh] = f2bf(acc[mt][nt][r]);
                }
            }
        }
    }
}

// ---------------- transpose-free MFMA flash attention ----------------
// block 64 (1 wave, no LDS/barriers); grid (32 bh, 128); strip = 127-blockIdx.y
// (longest first, LPT). Wave owns q-rows [strip*16, +16). Loop over 16-wide
// j-tiles: S^T via 4x MFMA16(K,Q); p = exp2(s*c1 - sl2*j) packed in-register
// as the P^T B-frag; O^T += MFMA16(V^T, P^T); l via MFMA16(ones, P^T).
__global__ __launch_bounds__(64) void attn_kernel(
    const ushort_t* __restrict__ Q, const ushort_t* __restrict__ K,
    const ushort_t* __restrict__ Vt, ushort_t* __restrict__ AO)
{
    const int lane = threadIdx.x & 63;
    const int quad = lane >> 4, l15 = lane & 15;
    const int bh   = blockIdx.x;
    const int h    = bh & 15, b = bh >> 4;
    const int strip = 127 - (int)blockIdx.y;
    const int qbase = strip * 16;

    const ushort_t* Qh = Q  + (size_t)bh * 2048 * 64;
    const ushort_t* Kh = K  + (size_t)bh * 2048 * 64;
    const ushort_t* Vh = Vt + (size_t)bh * 64 * 2048;

    const float LOG2E = 1.44269504088896340736f;
    const float sl2 = exp2f(-0.5f * (float)(h + 1)) * LOG2E;   // slope*log2e
    const float c1  = 0.125f * LOG2E;                          // DH^-0.5*log2e

    // Q^T B-frags (loop-invariant): lane(l15=i, quad): Q[qbase+l15][kc*16+quad*4+..3]
    s4 qf[4];
    #pragma unroll
    for (int kc = 0; kc < 4; ++kc)
        qf[kc] = *(const s4*)(Qh + (size_t)(qbase + l15) * 64 + kc * 16 + quad * 4);

    s4 onesf;
    #pragma unroll
    for (int e = 0; e < 4; ++e) onesf[e] = (short)0x3F80;   // bf16 1.0

    f32x4 accv[4] = {};   // O^T C-frags: row d=dt*16+quad*4+r, col i=l15
    f32x4 accl = {};      // l[i] replicated over rows

    s4 kfA[4], vfA[4], kfB[4], vfB[4];

    auto load_tile = [&](int jt, s4 kf[4], s4 vf[4]) {
        #pragma unroll
        for (int kc = 0; kc < 4; ++kc)
            kf[kc] = *(const s4*)(Kh + (size_t)(jt * 16 + l15) * 64 + kc * 16 + quad * 4);
        #pragma unroll
        for (int dt = 0; dt < 4; ++dt)
            vf[dt] = *(const s4*)(Vh + (size_t)(dt * 16 + l15) * 2048 + jt * 16 + quad * 4);
    };
    auto compute_tile = [&](int jt, const s4 kf[4], const s4 vf[4], bool diag) {
        f32x4 sT = {};
        #pragma unroll
        for (int kc = 0; kc < 4; ++kc) sT = MFMA16(kf[kc], qf[kc], sT);
        unsigned u[4];
        #pragma unroll
        for (int r = 0; r < 4; ++r) {
            int j = jt * 16 + quad * 4 + r;
            float p = exp2f(fmaf(sT[r], c1, -sl2 * (float)j));
            if (diag && (quad * 4 + r) > l15) p = 0.0f;   // causal within diagonal tile
            u[r] = __builtin_bit_cast(unsigned, p) + 0x8000u;   // round-half-up to bf16
        }
        unsigned d0 = (u[0] >> 16) | (u[1] & 0xFFFF0000u);
        unsigned d1 = (u[2] >> 16) | (u[3] & 0xFFFF0000u);
        uint2 dd = { d0, d1 };
        s4 pf = __builtin_bit_cast(s4, dd);   // P^T B-frag: k=quad*4+r, n=l15
        accl = MFMA16(onesf, pf, accl);
        #pragma unroll
        for (int dt = 0; dt < 4; ++dt) accv[dt] = MFMA16(vf[dt], pf, accv[dt]);
    };

    load_tile(0, kfA, vfA);
    int jt = 0;
    for (; jt + 2 <= strip; jt += 2) {
        load_tile(jt + 1, kfB, vfB);
        compute_tile(jt, kfA, vfA, false);
        load_tile(jt + 2, kfA, vfA);
        compute_tile(jt + 1, kfB, vfB, false);
    }
    if (jt < strip) {
        load_tile(jt + 1, kfB, vfB);     // jt+1 == strip (diagonal)
        compute_tile(jt, kfA, vfA, false);
        compute_tile(strip, kfB, vfB, true);
    } else {
        compute_tile(strip, kfA, vfA, true);
    }

    const float inv = 1.0f / fmaxf(accl[0], 1e-30f);
    const int i = qbase + l15;
    const size_t obase = ((size_t)(b * 2048 + i)) * 1024 + h * 64;
    #pragma unroll
    for (int dt = 0; dt < 4; ++dt) {
        ushort_t pk[4];
        #pragma unroll
        for (int r = 0; r < 4; ++r) pk[r] = f2bf(accv[dt][r] * inv);
        *(ushort2*)(AO + obase + dt * 16 + quad * 4)     = *(ushort2*)&pk[0];
        *(ushort2*)(AO + obase + dt * 16 + quad * 4 + 2) = *(ushort2*)&pk[2];
    }
}

// ---------------- Output projection GEMM + bias, W^T input -> FP32 ----------------
__global__ __launch_bounds__(256) void oproj_gemm(
    const ushort_t* __restrict__ A, const ushort_t* __restrict__ WT,
    const ushort_t* __restrict__ bias, float* __restrict__ out)
{
    __shared__ ushort_t As[128 * 40];
    __shared__ ushort_t Bs[128 * 40];

    const int tid  = threadIdx.x;
    const int m0   = blockIdx.y * 128, n0 = blockIdx.x * 128;
    const int lane = tid & 63, wv = tid >> 6;
    const int quad = lane >> 4, l15 = lane & 15;
    const int wm = (wv & 1) * 64, wn = (wv >> 1) * 64;

    const int ar = tid >> 1, ac = (tid & 1) * 16;

    f32x4 acc[4][4] = {};

    uint4 ra0 = *(const uint4*)(A  + (size_t)(m0 + ar) * 1024 + ac);
    uint4 ra1 = *(const uint4*)(A  + (size_t)(m0 + ar) * 1024 + ac + 8);
    uint4 rb0 = *(const uint4*)(WT + (size_t)(n0 + ar) * 1024 + ac);
    uint4 rb1 = *(const uint4*)(WT + (size_t)(n0 + ar) * 1024 + ac + 8);

    for (int kt = 0; kt < 32; ++kt) {
        __syncthreads();
        *(uint4*)(As + ar * 40 + ac)     = ra0;
        *(uint4*)(As + ar * 40 + ac + 8) = ra1;
        *(uint4*)(Bs + ar * 40 + ac)     = rb0;
        *(uint4*)(Bs + ar * 40 + ac + 8) = rb1;
        __syncthreads();
        if (kt < 31) {
            int k0 = (kt + 1) * 32;
            ra0 = *(const uint4*)(A  + (size_t)(m0 + ar) * 1024 + k0 + ac);
            ra1 = *(const uint4*)(A  + (size_t)(m0 + ar) * 1024 + k0 + ac + 8);
            rb0 = *(const uint4*)(WT + (size_t)(n0 + ar) * 1024 + k0 + ac);
            rb1 = *(const uint4*)(WT + (size_t)(n0 + ar) * 1024 + k0 + ac + 8);
        }
        bf16x8 af[4], bfr[4];
        #pragma unroll
        for (int t = 0; t < 4; ++t) {
            af[t]  = *(const bf16x8*)(As + (wm + t * 16 + l15) * 40 + quad * 8);
            bfr[t] = *(const bf16x8*)(Bs + (wn + t * 16 + l15) * 40 + quad * 8);
        }
        #pragma unroll
        for (int mt = 0; mt < 4; ++mt)
            #pragma unroll
            for (int nt = 0; nt < 4; ++nt)
                acc[mt][nt] = MFMA_16x16x32(af[mt], bfr[nt], acc[mt][nt]);
    }

    #pragma unroll
    for (int mt = 0; mt < 4; ++mt) {
        #pragma unroll
        for (int nt = 0; nt < 4; ++nt) {
            #pragma unroll
            for (int r = 0; r < 4; ++r) {
                int m = m0 + wm + mt * 16 + quad * 4 + r;
                int c = n0 + wn + nt * 16 + l15;
                out[(size_t)m * 1024 + c] = acc[mt][nt][r] + bf2f(bias[c]);
            }
        }
    }
}

extern "C" void kernel_launch(void* const* d_in, const int* in_sizes, int n_in,
                              void* d_out, int out_size, void* d_ws, size_t ws_size,
                              hipStream_t stream) {
    const void* X  = d_in[0];
    const void* Wq = d_in[1];
    const void* Wk = d_in[2];
    const void* Wv = d_in[3];
    const void* Wo = d_in[4];
    const void* bo = d_in[5];

    const size_t M = 1024 * 1024;
    ushort_t* ws  = (ushort_t*)d_ws;
    ushort_t* Qb  = ws;             // 4M elems
    ushort_t* Kb  = ws + 4 * M;
    ushort_t* Vt  = ws + 8 * M;
    ushort_t* Xc  = ws + 12 * M;    // shared with AO (Xc dead after qkv_gemm)
    ushort_t* AO  = ws + 12 * M;
    ushort_t* WqT = ws + 16 * M;
    ushort_t* WkT = ws + 17 * M;
    ushort_t* WvT = ws + 18 * M;
    ushort_t* WoT = ws + 19 * M;
    ushort_t* boc = ws + 20 * M;
    float* out = (float*)d_out;

    convert_x<<<2049, 256, 0, stream>>>(X, Wq, bo, Xc, boc);
    transpose_w<<<dim3(16, 16, 4), 256, 0, stream>>>(Wq, Wk, Wv, Wo, WqT, WkT, WvT, WoT);
    qkv_gemm<<<dim3(8, 32, 3), 256, 0, stream>>>(Xc, WqT, WkT, WvT, Qb, Kb, Vt);
    attn_kernel<<<dim3(32, 128), 64, 0, stream>>>(Qb, Kb, Vt, AO);
    oproj_gemm<<<dim3(8, 32), 256, 0, stream>>>(AO, WoT, boc, out);
}

// Round 11
// 198.015 us; speedup vs baseline: 1.9949x; 1.9949x over previous
//
#include <hip/hip_runtime.h>
#include <hip/hip_bf16.h>

// B=2, N=2048, D=1024, H=16, DH=64. Output fp32; inputs runtime-detected and
// converted once. R11 == R10 with the attn LDS stride fixed: 64x64 K/V tiles
// need stride 72 shorts (R10's stride 36 self-corrupted the tile -> absmax 2.02).
//
// ws (bf16 elems): Q@0(4M), K@4M, Vt@8M, Xc/AO@12M (shared), WqT@16M..WoT@19M,
// boc@20M. ~40MB.

typedef __bf16 bf16x8 __attribute__((ext_vector_type(8)));
typedef float f32x4 __attribute__((ext_vector_type(4)));
typedef short s4 __attribute__((ext_vector_type(4)));      // k16 MFMA A/B frag
typedef unsigned short ushort_t;

#define MFMA_16x16x32(a, b, c) __builtin_amdgcn_mfma_f32_16x16x32_bf16(a, b, c, 0, 0, 0)
#define MFMA16(a, b, c) __builtin_amdgcn_mfma_f32_16x16x16bf16_1k(a, b, c, 0, 0, 0)

__device__ __forceinline__ ushort_t f2bf(float f) {
    __hip_bfloat16 h = __float2bfloat16(f);
    return __builtin_bit_cast(ushort_t, h);
}
__device__ __forceinline__ float bf2f(ushort_t u) {
    unsigned x = ((unsigned)u) << 16;
    return __builtin_bit_cast(float, x);
}

__device__ __forceinline__ unsigned detect_fp32(const void* wp) {
    const ushort_t* w = (const ushort_t*)wp;
    unsigned c = 0;
    #pragma unroll
    for (int i = 0; i < 128; ++i) c += (((w[i] >> 7) & 0xFF) >= 0x7F) ? 1u : 0u;
    return (c > 8) ? 1u : 0u;
}

__device__ __forceinline__ uint4 load8(const void* p, size_t idx, unsigned flag) {
    if (flag) {
        const float* f = (const float*)p + idx;
        float4 a = *(const float4*)f;
        float4 b = *(const float4*)(f + 4);
        ushort_t u[8] = { f2bf(a.x), f2bf(a.y), f2bf(a.z), f2bf(a.w),
                          f2bf(b.x), f2bf(b.y), f2bf(b.z), f2bf(b.w) };
        return *(uint4*)u;
    }
    return *(const uint4*)((const ushort_t*)p + idx);
}

// ---------------- convert X + bias ----------------
__global__ __launch_bounds__(256) void convert_x(
    const void* __restrict__ X, const void* __restrict__ Wq, const void* __restrict__ bo,
    ushort_t* __restrict__ Xc, ushort_t* __restrict__ boc)
{
    const unsigned flag = detect_fp32(Wq);
    const int blk = blockIdx.x;
    if (blk < 2048) {
        size_t idx = (size_t)blk * 2048 + (size_t)threadIdx.x * 8;
        *(uint4*)(Xc + idx) = load8(X, idx, flag);
    } else {
        size_t idx = (size_t)threadIdx.x * 8;
        if (idx < 1024) *(uint4*)(boc + idx) = load8(bo, idx, flag);
    }
}

// ---------------- transpose weights -> WT[n][k] ----------------
__global__ __launch_bounds__(256) void transpose_w(
    const void* __restrict__ Wq, const void* __restrict__ Wk,
    const void* __restrict__ Wv, const void* __restrict__ Wo,
    ushort_t* __restrict__ WqT, ushort_t* __restrict__ WkT,
    ushort_t* __restrict__ WvT, ushort_t* __restrict__ WoT)
{
    __shared__ ushort_t T[64][72];
    const unsigned flag = detect_fp32(Wq);
    const int z = blockIdx.z;
    const void* W = (z == 0) ? Wq : ((z == 1) ? Wk : ((z == 2) ? Wv : Wo));
    ushort_t* WT = (z == 0) ? WqT : ((z == 1) ? WkT : ((z == 2) ? WvT : WoT));

    const int k0 = blockIdx.y * 64, n0 = blockIdx.x * 64;
    const int r = threadIdx.x >> 2, c = (threadIdx.x & 3) * 16;

    *(uint4*)&T[r][c]     = load8(W, (size_t)(k0 + r) * 1024 + n0 + c,     flag);
    *(uint4*)&T[r][c + 8] = load8(W, (size_t)(k0 + r) * 1024 + n0 + c + 8, flag);
    __syncthreads();
    ushort_t tmp[16];
    #pragma unroll
    for (int j = 0; j < 16; ++j) tmp[j] = T[c + j][r];
    *(uint4*)(WT + (size_t)(n0 + r) * 1024 + k0 + c)     = *(uint4*)&tmp[0];
    *(uint4*)(WT + (size_t)(n0 + r) * 1024 + k0 + c + 8) = *(uint4*)&tmp[8];
}

// ---------------- QKV projection GEMM, 128x128, W^T input ----------------
__global__ __launch_bounds__(256) void qkv_gemm(
    const ushort_t* __restrict__ X, const ushort_t* __restrict__ WqT,
    const ushort_t* __restrict__ WkT, const ushort_t* __restrict__ WvT,
    ushort_t* __restrict__ Q, ushort_t* __restrict__ K, ushort_t* __restrict__ Vt)
{
    __shared__ ushort_t As[128 * 40];
    __shared__ ushort_t Bs[128 * 40];

    const int z = blockIdx.z;
    const ushort_t* WT = (z == 0) ? WqT : ((z == 1) ? WkT : WvT);

    const int tid  = threadIdx.x;
    const int m0   = blockIdx.y * 128, n0 = blockIdx.x * 128;
    const int lane = tid & 63, wv = tid >> 6;
    const int quad = lane >> 4, l15 = lane & 15;
    const int wm = (wv & 1) * 64, wn = (wv >> 1) * 64;
    const int ar = tid >> 1, ac = (tid & 1) * 16;

    f32x4 acc[4][4] = {};

    uint4 ra0 = *(const uint4*)(X  + (size_t)(m0 + ar) * 1024 + ac);
    uint4 ra1 = *(const uint4*)(X  + (size_t)(m0 + ar) * 1024 + ac + 8);
    uint4 rb0 = *(const uint4*)(WT + (size_t)(n0 + ar) * 1024 + ac);
    uint4 rb1 = *(const uint4*)(WT + (size_t)(n0 + ar) * 1024 + ac + 8);

    for (int kt = 0; kt < 32; ++kt) {
        __syncthreads();
        *(uint4*)(As + ar * 40 + ac)     = ra0;
        *(uint4*)(As + ar * 40 + ac + 8) = ra1;
        *(uint4*)(Bs + ar * 40 + ac)     = rb0;
        *(uint4*)(Bs + ar * 40 + ac + 8) = rb1;
        __syncthreads();
        if (kt < 31) {
            int k0 = (kt + 1) * 32;
            ra0 = *(const uint4*)(X  + (size_t)(m0 + ar) * 1024 + k0 + ac);
            ra1 = *(const uint4*)(X  + (size_t)(m0 + ar) * 1024 + k0 + ac + 8);
            rb0 = *(const uint4*)(WT + (size_t)(n0 + ar) * 1024 + k0 + ac);
            rb1 = *(const uint4*)(WT + (size_t)(n0 + ar) * 1024 + k0 + ac + 8);
        }
        bf16x8 af[4], bfr[4];
        #pragma unroll
        for (int t = 0; t < 4; ++t) {
            af[t]  = *(const bf16x8*)(As + (wm + t * 16 + l15) * 40 + quad * 8);
            bfr[t] = *(const bf16x8*)(Bs + (wn + t * 16 + l15) * 40 + quad * 8);
        }
        #pragma unroll
        for (int mt = 0; mt < 4; ++mt)
            #pragma unroll
            for (int nt = 0; nt < 4; ++nt)
                acc[mt][nt] = MFMA_16x16x32(af[mt], bfr[nt], acc[mt][nt]);
    }

    #pragma unroll
    for (int mt = 0; mt < 4; ++mt) {
        #pragma unroll
        for (int nt = 0; nt < 4; ++nt) {
            if (z == 2) {
                int c  = n0 + wn + nt * 16 + l15;
                int h  = c >> 6, dh = c & 63;
                int mA = m0 + wm + mt * 16 + quad * 4;
                int b  = mA >> 11, nseq = mA & 2047;
                ushort_t pk[4];
                #pragma unroll
                for (int r = 0; r < 4; ++r) pk[r] = f2bf(acc[mt][nt][r]);
                *(ushort2*)(Vt + ((size_t)((b * 16 + h) * 64 + dh)) * 2048 + nseq)     = *(ushort2*)&pk[0];
                *(ushort2*)(Vt + ((size_t)((b * 16 + h) * 64 + dh)) * 2048 + nseq + 2) = *(ushort2*)&pk[2];
            } else {
                ushort_t* dst = (z == 0) ? Q : K;
                #pragma unroll
                for (int r = 0; r < 4; ++r) {
                    int m = m0 + wm + mt * 16 + quad * 4 + r;
                    int c = n0 + wn + nt * 16 + l15;
                    int b = m >> 11, nseq = m & 2047;
                    int h = c >> 6, dh = c & 63;
                    dst[((size_t)((b * 16 + h) * 2048 + nseq)) * 64 + dh] = f2bf(acc[mt][nt][r]);
                }
            }
        }
    }
}

// ---------------- MFMA flash attention: LDS-shared K/V + k16 identity ----------------
// grid (32 bh, 32 q-blocks), block 256 = 4 waves. qb = 31-blockIdx.y (LPT).
// Block owns q-rows [qb*64, +64); wave wv owns [qb*64+wv*16, +16).
// Per 64-j tile: stage K[j][d], V^T[d][j] into LDS (stride 72 shorts);
// per 16-j subtile: S^T via 2 MFMA32 (A=K LDS, B=Q regs) -> p=exp2(s*c1-sl2*j)
// packed in-register as P^T B-frag (R9-verified identity) ->
// accl += MFMA16(ones,pf); accv[dt] += MFMA16(V^T frag, pf).
__global__ __launch_bounds__(256) void attn_kernel(
    const ushort_t* __restrict__ Q, const ushort_t* __restrict__ K,
    const ushort_t* __restrict__ Vt, ushort_t* __restrict__ AO)
{
    __shared__ ushort_t Ks[64 * 72];   // [j 0..63][d 0..63], stride 72
    __shared__ ushort_t Vs[64 * 72];   // [d 0..63][j 0..63], stride 72

    const int tid  = threadIdx.x;
    const int wv   = tid >> 6, lane = tid & 63;
    const int quad = lane >> 4, l15 = lane & 15;
    const int bh   = blockIdx.x, h = bh & 15, b = bh >> 4;
    const int qb   = 31 - (int)blockIdx.y;
    const int iw   = qb * 64 + wv * 16;          // wave q-row base
    const int i_   = iw + l15;                   // this lane's q-row (S^T col)

    const ushort_t* Qh = Q  + (size_t)bh * 2048 * 64;
    const ushort_t* Kh = K  + (size_t)bh * 2048 * 64;
    const ushort_t* Vh = Vt + (size_t)bh * 64 * 2048;

    const float LOG2E = 1.44269504088896340736f;
    const float sl2 = exp2f(-0.5f * (float)(h + 1)) * LOG2E;
    const float c1  = 0.125f * LOG2E;

    // Q B-frags for S^T MFMA32: B^T[n=i=l15][k=d=quad*8+e]
    bf16x8 qf0 = *(const bf16x8*)(Qh + (size_t)(iw + l15) * 64 + quad * 8);
    bf16x8 qf1 = *(const bf16x8*)(Qh + (size_t)(iw + l15) * 64 + 32 + quad * 8);

    s4 onesf;
    #pragma unroll
    for (int e = 0; e < 4; ++e) onesf[e] = (short)0x3F80;

    f32x4 accv[4] = {};   // O^T: row d=dt*16+quad*4+r, col i=l15
    f32x4 accl = {};

    const int sr = tid >> 2, sc = (tid & 3) * 16;   // staging: row, col
    const int ntiles = qb + 1;

    uint4 ka0, ka1, va0, va1;
    {
        ka0 = *(const uint4*)(Kh + (size_t)sr * 64 + sc);
        ka1 = *(const uint4*)(Kh + (size_t)sr * 64 + sc + 8);
        va0 = *(const uint4*)(Vh + (size_t)sr * 2048 + sc);
        va1 = *(const uint4*)(Vh + (size_t)sr * 2048 + sc + 8);
    }

    for (int jt = 0; jt < ntiles; ++jt) {
        __syncthreads();
        *(uint4*)(Ks + sr * 72 + sc)     = ka0;
        *(uint4*)(Ks + sr * 72 + sc + 8) = ka1;
        *(uint4*)(Vs + sr * 72 + sc)     = va0;
        *(uint4*)(Vs + sr * 72 + sc + 8) = va1;
        __syncthreads();
        if (jt + 1 < ntiles) {
            int j0n = (jt + 1) * 64;
            ka0 = *(const uint4*)(Kh + (size_t)(j0n + sr) * 64 + sc);
            ka1 = *(const uint4*)(Kh + (size_t)(j0n + sr) * 64 + sc + 8);
            va0 = *(const uint4*)(Vh + (size_t)sr * 2048 + j0n + sc);
            va1 = *(const uint4*)(Vh + (size_t)sr * 2048 + j0n + sc + 8);
        }
        const bool dtile = (jt == qb);
        #pragma unroll
        for (int js = 0; js < 4; ++js) {
            const int j0s = jt * 64 + js * 16;
            if (dtile && j0s > iw + 15) break;   // wave-uniform: fully masked
            f32x4 sT = {};
            bf16x8 kf0 = *(const bf16x8*)(Ks + (js * 16 + l15) * 72 + quad * 8);
            bf16x8 kf1 = *(const bf16x8*)(Ks + (js * 16 + l15) * 72 + 32 + quad * 8);
            sT = MFMA_16x16x32(kf0, qf0, sT);
            sT = MFMA_16x16x32(kf1, qf1, sT);
            unsigned u[4];
            #pragma unroll
            for (int r = 0; r < 4; ++r) {
                int j = j0s + quad * 4 + r;
                float p = exp2f(fmaf(sT[r], c1, -sl2 * (float)j));
                if (dtile && j > i_) p = 0.0f;
                u[r] = __builtin_bit_cast(unsigned, p) + 0x8000u;
            }
            uint2 dd = { (u[0] >> 16) | (u[1] & 0xFFFF0000u),
                         (u[2] >> 16) | (u[3] & 0xFFFF0000u) };
            s4 pf = __builtin_bit_cast(s4, dd);   // P^T B-frag: k=quad*4+r, n=l15
            accl = MFMA16(onesf, pf, accl);
            #pragma unroll
            for (int dt = 0; dt < 4; ++dt) {
                s4 vf = *(const s4*)(Vs + (dt * 16 + l15) * 72 + js * 16 + quad * 4);
                accv[dt] = MFMA16(vf, pf, accv[dt]);
            }
        }
    }

    const float inv = 1.0f / fmaxf(accl[0], 1e-30f);
    const size_t obase = ((size_t)(b * 2048 + i_)) * 1024 + h * 64;
    #pragma unroll
    for (int dt = 0; dt < 4; ++dt) {
        ushort_t pk[4];
        #pragma unroll
        for (int r = 0; r < 4; ++r) pk[r] = f2bf(accv[dt][r] * inv);
        *(ushort2*)(AO + obase + dt * 16 + quad * 4)     = *(ushort2*)&pk[0];
        *(ushort2*)(AO + obase + dt * 16 + quad * 4 + 2) = *(ushort2*)&pk[2];
    }
}

// ---------------- Output projection GEMM + bias, W^T input -> FP32 ----------------
__global__ __launch_bounds__(256) void oproj_gemm(
    const ushort_t* __restrict__ A, const ushort_t* __restrict__ WT,
    const ushort_t* __restrict__ bias, float* __restrict__ out)
{
    __shared__ ushort_t As[128 * 40];
    __shared__ ushort_t Bs[128 * 40];

    const int tid  = threadIdx.x;
    const int m0   = blockIdx.y * 128, n0 = blockIdx.x * 128;
    const int lane = tid & 63, wv = tid >> 6;
    const int quad = lane >> 4, l15 = lane & 15;
    const int wm = (wv & 1) * 64, wn = (wv >> 1) * 64;
    const int ar = tid >> 1, ac = (tid & 1) * 16;

    f32x4 acc[4][4] = {};

    uint4 ra0 = *(const uint4*)(A  + (size_t)(m0 + ar) * 1024 + ac);
    uint4 ra1 = *(const uint4*)(A  + (size_t)(m0 + ar) * 1024 + ac + 8);
    uint4 rb0 = *(const uint4*)(WT + (size_t)(n0 + ar) * 1024 + ac);
    uint4 rb1 = *(const uint4*)(WT + (size_t)(n0 + ar) * 1024 + ac + 8);

    for (int kt = 0; kt < 32; ++kt) {
        __syncthreads();
        *(uint4*)(As + ar * 40 + ac)     = ra0;
        *(uint4*)(As + ar * 40 + ac + 8) = ra1;
        *(uint4*)(Bs + ar * 40 + ac)     = rb0;
        *(uint4*)(Bs + ar * 40 + ac + 8) = rb1;
        __syncthreads();
        if (kt < 31) {
            int k0 = (kt + 1) * 32;
            ra0 = *(const uint4*)(A  + (size_t)(m0 + ar) * 1024 + k0 + ac);
            ra1 = *(const uint4*)(A  + (size_t)(m0 + ar) * 1024 + k0 + ac + 8);
            rb0 = *(const uint4*)(WT + (size_t)(n0 + ar) * 1024 + k0 + ac);
            rb1 = *(const uint4*)(WT + (size_t)(n0 + ar) * 1024 + k0 + ac + 8);
        }
        bf16x8 af[4], bfr[4];
        #pragma unroll
        for (int t = 0; t < 4; ++t) {
            af[t]  = *(const bf16x8*)(As + (wm + t * 16 + l15) * 40 + quad * 8);
            bfr[t] = *(const bf16x8*)(Bs + (wn + t * 16 + l15) * 40 + quad * 8);
        }
        #pragma unroll
        for (int mt = 0; mt < 4; ++mt)
            #pragma unroll
            for (int nt = 0; nt < 4; ++nt)
                acc[mt][nt] = MFMA_16x16x32(af[mt], bfr[nt], acc[mt][nt]);
    }

    #pragma unroll
    for (int mt = 0; mt < 4; ++mt) {
        #pragma unroll
        for (int nt = 0; nt < 4; ++nt) {
            #pragma unroll
            for (int r = 0; r < 4; ++r) {
                int m = m0 + wm + mt * 16 + quad * 4 + r;
                int c = n0 + wn + nt * 16 + l15;
                out[(size_t)m * 1024 + c] = acc[mt][nt][r] + bf2f(bias[c]);
            }
        }
    }
}

extern "C" void kernel_launch(void* const* d_in, const int* in_sizes, int n_in,
                              void* d_out, int out_size, void* d_ws, size_t ws_size,
                              hipStream_t stream) {
    const void* X  = d_in[0];
    const void* Wq = d_in[1];
    const void* Wk = d_in[2];
    const void* Wv = d_in[3];
    const void* Wo = d_in[4];
    const void* bo = d_in[5];

    const size_t M = 1024 * 1024;
    ushort_t* ws  = (ushort_t*)d_ws;
    ushort_t* Qb  = ws;
    ushort_t* Kb  = ws + 4 * M;
    ushort_t* Vt  = ws + 8 * M;
    ushort_t* Xc  = ws + 12 * M;    // shared with AO
    ushort_t* AO  = ws + 12 * M;
    ushort_t* WqT = ws + 16 * M;
    ushort_t* WkT = ws + 17 * M;
    ushort_t* WvT = ws + 18 * M;
    ushort_t* WoT = ws + 19 * M;
    ushort_t* boc = ws + 20 * M;
    float* out = (float*)d_out;

    convert_x<<<2049, 256, 0, stream>>>(X, Wq, bo, Xc, boc);
    transpose_w<<<dim3(16, 16, 4), 256, 0, stream>>>(Wq, Wk, Wv, Wo, WqT, WkT, WvT, WoT);
    qkv_gemm<<<dim3(8, 32, 3), 256, 0, stream>>>(Xc, WqT, WkT, WvT, Qb, Kb, Vt);
    attn_kernel<<<dim3(32, 32), 256, 0, stream>>>(Qb, Kb, Vt, AO);
    oproj_gemm<<<dim3(8, 32), 256, 0, stream>>>(AO, WoT, boc, out);
}

// Round 12
// 194.507 us; speedup vs baseline: 2.0309x; 1.0180x over previous
//
#include <hip/hip_runtime.h>
#include <hip/hip_bf16.h>

// B=2, N=2048, D=1024, H=16, DH=64. Output fp32; inputs runtime-detected and
// converted once. R12: (a) qkv/oproj staging via global_load_lds width=16
// (m97 ladder step) with XOR chunk swizzle (store c^((r>>1)&3)) replacing
// padding; (b) attn diagonal-tile specialization (branch-free main subtiles).
//
// ws (bf16 elems): Q@0(4M), K@4M, Vt@8M, Xc/AO@12M (shared), WqT@16M..WoT@19M,
// boc@20M. ~40MB.

typedef __bf16 bf16x8 __attribute__((ext_vector_type(8)));
typedef float f32x4 __attribute__((ext_vector_type(4)));
typedef short s4 __attribute__((ext_vector_type(4)));      // k16 MFMA A/B frag
typedef unsigned short ushort_t;

#define MFMA_16x16x32(a, b, c) __builtin_amdgcn_mfma_f32_16x16x32_bf16(a, b, c, 0, 0, 0)
#define MFMA16(a, b, c) __builtin_amdgcn_mfma_f32_16x16x16bf16_1k(a, b, c, 0, 0, 0)

__device__ __forceinline__ ushort_t f2bf(float f) {
    __hip_bfloat16 h = __float2bfloat16(f);
    return __builtin_bit_cast(ushort_t, h);
}
__device__ __forceinline__ float bf2f(ushort_t u) {
    unsigned x = ((unsigned)u) << 16;
    return __builtin_bit_cast(float, x);
}

// async global->LDS, 16B/lane; LDS dest = wave-uniform base + lane*16.
__device__ __forceinline__ void gl_lds16(const ushort_t* g, ushort_t* l) {
    __builtin_amdgcn_global_load_lds(
        (const __attribute__((address_space(1))) void*)g,
        (__attribute__((address_space(3))) void*)l, 16, 0, 0);
}

__device__ __forceinline__ unsigned detect_fp32(const void* wp) {
    const ushort_t* w = (const ushort_t*)wp;
    unsigned c = 0;
    #pragma unroll
    for (int i = 0; i < 128; ++i) c += (((w[i] >> 7) & 0xFF) >= 0x7F) ? 1u : 0u;
    return (c > 8) ? 1u : 0u;
}

__device__ __forceinline__ uint4 load8(const void* p, size_t idx, unsigned flag) {
    if (flag) {
        const float* f = (const float*)p + idx;
        float4 a = *(const float4*)f;
        float4 b = *(const float4*)(f + 4);
        ushort_t u[8] = { f2bf(a.x), f2bf(a.y), f2bf(a.z), f2bf(a.w),
                          f2bf(b.x), f2bf(b.y), f2bf(b.z), f2bf(b.w) };
        return *(uint4*)u;
    }
    return *(const uint4*)((const ushort_t*)p + idx);
}

// ---------------- convert X + bias ----------------
__global__ __launch_bounds__(256) void convert_x(
    const void* __restrict__ X, const void* __restrict__ Wq, const void* __restrict__ bo,
    ushort_t* __restrict__ Xc, ushort_t* __restrict__ boc)
{
    const unsigned flag = detect_fp32(Wq);
    const int blk = blockIdx.x;
    if (blk < 2048) {
        size_t idx = (size_t)blk * 2048 + (size_t)threadIdx.x * 8;
        *(uint4*)(Xc + idx) = load8(X, idx, flag);
    } else {
        size_t idx = (size_t)threadIdx.x * 8;
        if (idx < 1024) *(uint4*)(boc + idx) = load8(bo, idx, flag);
    }
}

// ---------------- transpose weights -> WT[n][k] ----------------
__global__ __launch_bounds__(256) void transpose_w(
    const void* __restrict__ Wq, const void* __restrict__ Wk,
    const void* __restrict__ Wv, const void* __restrict__ Wo,
    ushort_t* __restrict__ WqT, ushort_t* __restrict__ WkT,
    ushort_t* __restrict__ WvT, ushort_t* __restrict__ WoT)
{
    __shared__ ushort_t T[64][72];
    const unsigned flag = detect_fp32(Wq);
    const int z = blockIdx.z;
    const void* W = (z == 0) ? Wq : ((z == 1) ? Wk : ((z == 2) ? Wv : Wo));
    ushort_t* WT = (z == 0) ? WqT : ((z == 1) ? WkT : ((z == 2) ? WvT : WoT));

    const int k0 = blockIdx.y * 64, n0 = blockIdx.x * 64;
    const int r = threadIdx.x >> 2, c = (threadIdx.x & 3) * 16;

    *(uint4*)&T[r][c]     = load8(W, (size_t)(k0 + r) * 1024 + n0 + c,     flag);
    *(uint4*)&T[r][c + 8] = load8(W, (size_t)(k0 + r) * 1024 + n0 + c + 8, flag);
    __syncthreads();
    ushort_t tmp[16];
    #pragma unroll
    for (int j = 0; j < 16; ++j) tmp[j] = T[c + j][r];
    *(uint4*)(WT + (size_t)(n0 + r) * 1024 + k0 + c)     = *(uint4*)&tmp[0];
    *(uint4*)(WT + (size_t)(n0 + r) * 1024 + k0 + c + 8) = *(uint4*)&tmp[8];
}

// ---------------- QKV projection GEMM, 128x128, global_load_lds staging ----------------
// grid (8, 32, 3), block 256 (4 waves), BK=32. Unpadded LDS 128x32 shorts.
// Swizzle: LDS (row r, chunk c) holds global k-chunk c^((r>>1)&3).
// Store side: lane l writes chunk l&3 of row (t*64+wv*16+(l>>2)) -> source
// chunk (l&3)^((l>>3)&3). Read side: row R=wm+t*16+l15 chunk q at position
// q^((l15>>1)&3). Conflict-free (8 dwords/bank = b128 minimum).
__global__ __launch_bounds__(256) void qkv_gemm(
    const ushort_t* __restrict__ X, const ushort_t* __restrict__ WqT,
    const ushort_t* __restrict__ WkT, const ushort_t* __restrict__ WvT,
    ushort_t* __restrict__ Q, ushort_t* __restrict__ K, ushort_t* __restrict__ Vt)
{
    __shared__ ushort_t As[128 * 32];
    __shared__ ushort_t Bs[128 * 32];

    const int z = blockIdx.z;
    const ushort_t* WT = (z == 0) ? WqT : ((z == 1) ? WkT : WvT);

    const int tid  = threadIdx.x;
    const int m0   = blockIdx.y * 128, n0 = blockIdx.x * 128;
    const int lane = tid & 63, wv = tid >> 6;
    const int quad = lane >> 4, l15 = lane & 15;
    const int wm = (wv & 1) * 64, wn = (wv >> 1) * 64;

    const int lrow = lane >> 2;                         // 0..15
    const int schk = (lane & 3) ^ ((lane >> 3) & 3);    // swizzled source chunk
    const int ra0_ = wv * 16 + lrow;                    // issue-0 row
    ushort_t* aB0 = As + wv * 512;                      // wave-uniform LDS bases
    ushort_t* aB1 = As + 2048 + wv * 512;
    ushort_t* bB0 = Bs + wv * 512;
    ushort_t* bB1 = Bs + 2048 + wv * 512;
    const int sp = quad ^ ((l15 >> 1) & 3);             // read chunk position

    f32x4 acc[4][4] = {};

    for (int kt = 0; kt < 32; ++kt) {
        const int k0 = kt * 32;
        __syncthreads();
        gl_lds16(X  + (size_t)(m0 + ra0_)      * 1024 + k0 + schk * 8, aB0);
        gl_lds16(X  + (size_t)(m0 + 64 + ra0_) * 1024 + k0 + schk * 8, aB1);
        gl_lds16(WT + (size_t)(n0 + ra0_)      * 1024 + k0 + schk * 8, bB0);
        gl_lds16(WT + (size_t)(n0 + 64 + ra0_) * 1024 + k0 + schk * 8, bB1);
        __syncthreads();   // compiler emits vmcnt(0) drain -> LDS data visible

        bf16x8 af[4], bfr[4];
        #pragma unroll
        for (int t = 0; t < 4; ++t) {
            af[t]  = *(const bf16x8*)(As + (wm + t * 16 + l15) * 32 + sp * 8);
            bfr[t] = *(const bf16x8*)(Bs + (wn + t * 16 + l15) * 32 + sp * 8);
        }
        #pragma unroll
        for (int mt = 0; mt < 4; ++mt)
            #pragma unroll
            for (int nt = 0; nt < 4; ++nt)
                acc[mt][nt] = MFMA_16x16x32(af[mt], bfr[nt], acc[mt][nt]);
    }

    #pragma unroll
    for (int mt = 0; mt < 4; ++mt) {
        #pragma unroll
        for (int nt = 0; nt < 4; ++nt) {
            if (z == 2) {
                int c  = n0 + wn + nt * 16 + l15;
                int h  = c >> 6, dh = c & 63;
                int mA = m0 + wm + mt * 16 + quad * 4;
                int b  = mA >> 11, nseq = mA & 2047;
                ushort_t pk[4];
                #pragma unroll
                for (int r = 0; r < 4; ++r) pk[r] = f2bf(acc[mt][nt][r]);
                *(ushort2*)(Vt + ((size_t)((b * 16 + h) * 64 + dh)) * 2048 + nseq)     = *(ushort2*)&pk[0];
                *(ushort2*)(Vt + ((size_t)((b * 16 + h) * 64 + dh)) * 2048 + nseq + 2) = *(ushort2*)&pk[2];
            } else {
                ushort_t* dst = (z == 0) ? Q : K;
                #pragma unroll
                for (int r = 0; r < 4; ++r) {
                    int m = m0 + wm + mt * 16 + quad * 4 + r;
                    int c = n0 + wn + nt * 16 + l15;
                    int b = m >> 11, nseq = m & 2047;
                    int h = c >> 6, dh = c & 63;
                    dst[((size_t)((b * 16 + h) * 2048 + nseq)) * 64 + dh] = f2bf(acc[mt][nt][r]);
                }
            }
        }
    }
}

// ---------------- MFMA flash attention: LDS-shared K/V + k16 identity ----------------
// grid (32 bh, 32 q-blocks), block 256 = 4 waves, qb = 31-blockIdx.y (LPT).
// Main tiles: branch-free subtiles; diagonal tile specialized (mask only there).
__global__ __launch_bounds__(256) void attn_kernel(
    const ushort_t* __restrict__ Q, const ushort_t* __restrict__ K,
    const ushort_t* __restrict__ Vt, ushort_t* __restrict__ AO)
{
    __shared__ ushort_t Ks[64 * 72];   // [j][d], stride 72
    __shared__ ushort_t Vs[64 * 72];   // [d][j], stride 72

    const int tid  = threadIdx.x;
    const int wv   = tid >> 6, lane = tid & 63;
    const int quad = lane >> 4, l15 = lane & 15;
    const int bh   = blockIdx.x, h = bh & 15, b = bh >> 4;
    const int qb   = 31 - (int)blockIdx.y;
    const int iw   = qb * 64 + wv * 16;
    const int i_   = iw + l15;

    const ushort_t* Qh = Q  + (size_t)bh * 2048 * 64;
    const ushort_t* Kh = K  + (size_t)bh * 2048 * 64;
    const ushort_t* Vh = Vt + (size_t)bh * 64 * 2048;

    const float LOG2E = 1.44269504088896340736f;
    const float sl2 = exp2f(-0.5f * (float)(h + 1)) * LOG2E;
    const float c1  = 0.125f * LOG2E;

    bf16x8 qf0 = *(const bf16x8*)(Qh + (size_t)(iw + l15) * 64 + quad * 8);
    bf16x8 qf1 = *(const bf16x8*)(Qh + (size_t)(iw + l15) * 64 + 32 + quad * 8);

    s4 onesf;
    #pragma unroll
    for (int e = 0; e < 4; ++e) onesf[e] = (short)0x3F80;

    f32x4 accv[4] = {};
    f32x4 accl = {};

    const int sr = tid >> 2, sc = (tid & 3) * 16;
    const int ntiles = qb + 1;

    uint4 ka0 = *(const uint4*)(Kh + (size_t)sr * 64 + sc);
    uint4 ka1 = *(const uint4*)(Kh + (size_t)sr * 64 + sc + 8);
    uint4 va0 = *(const uint4*)(Vh + (size_t)sr * 2048 + sc);
    uint4 va1 = *(const uint4*)(Vh + (size_t)sr * 2048 + sc + 8);

    auto subtile = [&](int jt, int js, bool masked) {
        const int j0s = jt * 64 + js * 16;
        f32x4 sT = {};
        bf16x8 kf0 = *(const bf16x8*)(Ks + (js * 16 + l15) * 72 + quad * 8);
        bf16x8 kf1 = *(const bf16x8*)(Ks + (js * 16 + l15) * 72 + 32 + quad * 8);
        sT = MFMA_16x16x32(kf0, qf0, sT);
        sT = MFMA_16x16x32(kf1, qf1, sT);
        unsigned u[4];
        #pragma unroll
        for (int r = 0; r < 4; ++r) {
            int j = j0s + quad * 4 + r;
            float p = exp2f(fmaf(sT[r], c1, -sl2 * (float)j));
            if (masked && j > i_) p = 0.0f;
            u[r] = __builtin_bit_cast(unsigned, p) + 0x8000u;
        }
        uint2 dd = { (u[0] >> 16) | (u[1] & 0xFFFF0000u),
                     (u[2] >> 16) | (u[3] & 0xFFFF0000u) };
        s4 pf = __builtin_bit_cast(s4, dd);
        accl = MFMA16(onesf, pf, accl);
        #pragma unroll
        for (int dt = 0; dt < 4; ++dt) {
            s4 vf = *(const s4*)(Vs + (dt * 16 + l15) * 72 + js * 16 + quad * 4);
            accv[dt] = MFMA16(vf, pf, accv[dt]);
        }
    };

    for (int jt = 0; jt < ntiles; ++jt) {
        __syncthreads();
        *(uint4*)(Ks + sr * 72 + sc)     = ka0;
        *(uint4*)(Ks + sr * 72 + sc + 8) = ka1;
        *(uint4*)(Vs + sr * 72 + sc)     = va0;
        *(uint4*)(Vs + sr * 72 + sc + 8) = va1;
        __syncthreads();
        if (jt + 1 < ntiles) {
            int j0n = (jt + 1) * 64;
            ka0 = *(const uint4*)(Kh + (size_t)(j0n + sr) * 64 + sc);
            ka1 = *(const uint4*)(Kh + (size_t)(j0n + sr) * 64 + sc + 8);
            va0 = *(const uint4*)(Vh + (size_t)sr * 2048 + j0n + sc);
            va1 = *(const uint4*)(Vh + (size_t)sr * 2048 + j0n + sc + 8);
        }
        if (jt < qb) {
            #pragma unroll
            for (int js = 0; js < 4; ++js) subtile(jt, js, false);
        } else {
            for (int js = 0; js < wv; ++js) subtile(jt, js, false);
            subtile(jt, wv, true);
        }
    }

    const float inv = 1.0f / fmaxf(accl[0], 1e-30f);
    const size_t obase = ((size_t)(b * 2048 + i_)) * 1024 + h * 64;
    #pragma unroll
    for (int dt = 0; dt < 4; ++dt) {
        ushort_t pk[4];
        #pragma unroll
        for (int r = 0; r < 4; ++r) pk[r] = f2bf(accv[dt][r] * inv);
        *(ushort2*)(AO + obase + dt * 16 + quad * 4)     = *(ushort2*)&pk[0];
        *(ushort2*)(AO + obase + dt * 16 + quad * 4 + 2) = *(ushort2*)&pk[2];
    }
}

// ---------------- Output projection GEMM + bias, global_load_lds -> FP32 ----------------
__global__ __launch_bounds__(256) void oproj_gemm(
    const ushort_t* __restrict__ A, const ushort_t* __restrict__ WT,
    const ushort_t* __restrict__ bias, float* __restrict__ out)
{
    __shared__ ushort_t As[128 * 32];
    __shared__ ushort_t Bs[128 * 32];

    const int tid  = threadIdx.x;
    const int m0   = blockIdx.y * 128, n0 = blockIdx.x * 128;
    const int lane = tid & 63, wv = tid >> 6;
    const int quad = lane >> 4, l15 = lane & 15;
    const int wm = (wv & 1) * 64, wn = (wv >> 1) * 64;

    const int lrow = lane >> 2;
    const int schk = (lane & 3) ^ ((lane >> 3) & 3);
    const int ra0_ = wv * 16 + lrow;
    ushort_t* aB0 = As + wv * 512;
    ushort_t* aB1 = As + 2048 + wv * 512;
    ushort_t* bB0 = Bs + wv * 512;
    ushort_t* bB1 = Bs + 2048 + wv * 512;
    const int sp = quad ^ ((l15 >> 1) & 3);

    f32x4 acc[4][4] = {};

    for (int kt = 0; kt < 32; ++kt) {
        const int k0 = kt * 32;
        __syncthreads();
        gl_lds16(A  + (size_t)(m0 + ra0_)      * 1024 + k0 + schk * 8, aB0);
        gl_lds16(A  + (size_t)(m0 + 64 + ra0_) * 1024 + k0 + schk * 8, aB1);
        gl_lds16(WT + (size_t)(n0 + ra0_)      * 1024 + k0 + schk * 8, bB0);
        gl_lds16(WT + (size_t)(n0 + 64 + ra0_) * 1024 + k0 + schk * 8, bB1);
        __syncthreads();

        bf16x8 af[4], bfr[4];
        #pragma unroll
        for (int t = 0; t < 4; ++t) {
            af[t]  = *(const bf16x8*)(As + (wm + t * 16 + l15) * 32 + sp * 8);
            bfr[t] = *(const bf16x8*)(Bs + (wn + t * 16 + l15) * 32 + sp * 8);
        }
        #pragma unroll
        for (int mt = 0; mt < 4; ++mt)
            #pragma unroll
            for (int nt = 0; nt < 4; ++nt)
                acc[mt][nt] = MFMA_16x16x32(af[mt], bfr[nt], acc[mt][nt]);
    }

    #pragma unroll
    for (int mt = 0; mt < 4; ++mt) {
        #pragma unroll
        for (int nt = 0; nt < 4; ++nt) {
            #pragma unroll
            for (int r = 0; r < 4; ++r) {
                int m = m0 + wm + mt * 16 + quad * 4 + r;
                int c = n0 + wn + nt * 16 + l15;
                out[(size_t)m * 1024 + c] = acc[mt][nt][r] + bf2f(bias[c]);
            }
        }
    }
}

extern "C" void kernel_launch(void* const* d_in, const int* in_sizes, int n_in,
                              void* d_out, int out_size, void* d_ws, size_t ws_size,
                              hipStream_t stream) {
    const void* X  = d_in[0];
    const void* Wq = d_in[1];
    const void* Wk = d_in[2];
    const void* Wv = d_in[3];
    const void* Wo = d_in[4];
    const void* bo = d_in[5];

    const size_t M = 1024 * 1024;
    ushort_t* ws  = (ushort_t*)d_ws;
    ushort_t* Qb  = ws;
    ushort_t* Kb  = ws + 4 * M;
    ushort_t* Vt  = ws + 8 * M;
    ushort_t* Xc  = ws + 12 * M;    // shared with AO (Xc dead after qkv_gemm)
    ushort_t* AO  = ws + 12 * M;
    ushort_t* WqT = ws + 16 * M;
    ushort_t* WkT = ws + 17 * M;
    ushort_t* WvT = ws + 18 * M;
    ushort_t* WoT = ws + 19 * M;
    ushort_t* boc = ws + 20 * M;
    float* out = (float*)d_out;

    convert_x<<<2049, 256, 0, stream>>>(X, Wq, bo, Xc, boc);
    transpose_w<<<dim3(16, 16, 4), 256, 0, stream>>>(Wq, Wk, Wv, Wo, WqT, WkT, WvT, WoT);
    qkv_gemm<<<dim3(8, 32, 3), 256, 0, stream>>>(Xc, WqT, WkT, WvT, Qb, Kb, Vt);
    attn_kernel<<<dim3(32, 32), 256, 0, stream>>>(Qb, Kb, Vt, AO);
    oproj_gemm<<<dim3(8, 32), 256, 0, stream>>>(AO, WoT, boc, out);
}